// Round 2
// baseline (549.537 us; speedup 1.0000x reference)
//
#include <hip/hip_runtime.h>
#include <math.h>

#define Himg 128
#define Wimg 128
#define HW   16384      // 128*128
#define Cin  64
#define Kk   9
#define OUTC 128
#define Bsz  8

// ---------------------------------------------------------------------------
// Kernel 0: repack w_conv[o][c][k] -> wpk[k][c][o]  (coalesced tile loads later)
// ---------------------------------------------------------------------------
__global__ __launch_bounds__(256) void repack_w(const float* __restrict__ w_conv,
                                                float* __restrict__ wpk) {
    int idx = blockIdx.x * 256 + threadIdx.x;            // 0 .. 73727
    if (idx >= Kk * Cin * OUTC) return;
    int o = idx % OUTC;
    int c = (idx / OUTC) % Cin;
    int k = idx / (OUTC * Cin);
    wpk[idx] = w_conv[(o * Cin + c) * 9 + k];
}

// ---------------------------------------------------------------------------
// Kernel 1: offset conv (18 ch) + mask conv (9 ch) + sigmoid.
// Block = 2 rows x 128 cols. Per channel, stage the 4 needed x rows in LDS
// (coalesced global loads), taps read LDS. Batch swizzled to XCD via bid&7.
// ---------------------------------------------------------------------------
__global__ __launch_bounds__(256) void offs_mask(
        const float* __restrict__ x,
        const float* __restrict__ w_offset, const float* __restrict__ b_offset,
        const float* __restrict__ w_mask,   const float* __restrict__ b_mask,
        float* __restrict__ dy_out, float* __restrict__ dx_out,
        float* __restrict__ mk_out) {
    __shared__ float xs[4][Wimg];          // rows h0-1 .. h0+2, 2 KB

    int t   = threadIdx.x;
    int bid = blockIdx.x;
    int b   = bid & 7;                     // XCD-batch swizzle
    int rp  = bid >> 3;                    // row pair 0..63
    int h0  = rp * 2;
    int hr  = t >> 7;                      // 0/1: output row h0+hr
    int w   = t & 127;
    int h   = h0 + hr;

    float acc[27];
#pragma unroll
    for (int j = 0; j < 18; ++j) acc[j] = b_offset[j];
#pragma unroll
    for (int j = 0; j < 9; ++j)  acc[18 + j] = b_mask[j];

    const float* xb = x + (size_t)b * Cin * HW;
    for (int c = 0; c < Cin; ++c) {
        __syncthreads();
        // stage rows h0-1 .. h0+2 (512 floats) cooperatively
#pragma unroll
        for (int i = 0; i < 2; ++i) {
            int idx = t + i * 256;         // 0..511
            int r   = idx >> 7;            // 0..3
            int col = idx & 127;
            int y   = h0 - 1 + r;
            xs[r][col] = (y >= 0 && y < Himg) ? xb[(size_t)c * HW + y * Wimg + col]
                                              : 0.0f;
        }
        __syncthreads();

        float xv[9];
#pragma unroll
        for (int ty = 0; ty < 3; ++ty) {
            int r = hr + ty;               // row (h-1+ty) is xs[hr+ty]
#pragma unroll
            for (int tx = 0; tx < 3; ++tx) {
                int xx = w - 1 + tx;
                xv[ty * 3 + tx] = (xx >= 0 && xx < Wimg) ? xs[r][xx] : 0.0f;
            }
        }
#pragma unroll
        for (int j = 0; j < 18; ++j) {
#pragma unroll
            for (int tp = 0; tp < 9; ++tp)
                acc[j] = fmaf(w_offset[(j * Cin + c) * 9 + tp], xv[tp], acc[j]);
        }
#pragma unroll
        for (int j = 0; j < 9; ++j) {
#pragma unroll
            for (int tp = 0; tp < 9; ++tp)
                acc[18 + j] = fmaf(w_mask[(j * Cin + c) * 9 + tp], xv[tp], acc[18 + j]);
        }
    }

    int rem = h * Wimg + w;
#pragma unroll
    for (int k = 0; k < 9; ++k) {
        int idx = (b * 9 + k) * HW + rem;
        dy_out[idx] = acc[2 * k];
        dx_out[idx] = acc[2 * k + 1];
        mk_out[idx] = 1.0f / (1.0f + expf(-acc[18 + k]));
    }
}

// ---------------------------------------------------------------------------
// Kernel 2: fused deformable sampling + einsum.
// Out(128 x Npix) = Wmat(128 x 576) * V(576 x Npix), V built on the fly.
// Changes vs R1:
//  - bid&7 batch swizzle: each XCD's L2 holds exactly one batch's x (4 MB).
//  - geometry (bilinear weights + offsets) precomputed ONCE into LDS.
//  - loop order: 16-channel chunk OUTER, k INNER -> the 9 taps re-read a
//    ~22 KB x region that stays L1-resident.
// ---------------------------------------------------------------------------
#define PPB 64
__global__ __launch_bounds__(256) void deform_gemm(
        const float* __restrict__ x, const float* __restrict__ wpk,
        const float* __restrict__ dy_ws, const float* __restrict__ dx_ws,
        const float* __restrict__ mk_ws, float* __restrict__ out) {
    __shared__ float v_tile[16][PPB];        // 4 KB
    __shared__ float w_tile[16][OUTC];       // 8 KB
    __shared__ float g_w00[Kk][PPB], g_w01[Kk][PPB];
    __shared__ float g_w10[Kk][PPB], g_w11[Kk][PPB];
    __shared__ int   g_o00[Kk][PPB];
    __shared__ int   g_pack[Kk][PPB];        // dx1 | (dyrow<<16)

    int t    = threadIdx.x;
    int bid  = blockIdx.x;
    int b    = bid & 7;                      // XCD-batch swizzle
    int pb   = bid >> 3;                     // 0..255
    int pix0 = pb * PPB;
    int h    = pix0 >> 7;                    // row (fixed per block)
    int w0   = pix0 & 127;                   // 0 or 64

    // sampling-role mapping
    int p  = t & 63;                         // pixel 0..63
    int cb = (t >> 6) * 4;                   // channel sub-base {0,4,8,12}
    // compute-role mapping
    int og = t >> 3;                         // output group 0..31 (4 outs)
    int pg = (t & 7) * 8;                    // pixel group start (8 pixels)

    // ---- geometry precompute: 576 items, once ----
    for (int it = t; it < Kk * PPB; it += 256) {
        int k  = it >> 6;
        int pp = it & 63;
        int sidx = (b * 9 + k) * HW + pix0 + pp;
        float dy = dy_ws[sidx];
        float dx = dx_ws[sidx];
        float mk = mk_ws[sidx];

        float gy  = (float)h + (float)(k / 3) - 1.0f + dy;
        float gx  = (float)(w0 + pp) + (float)(k % 3) - 1.0f + dx;
        float y0f = floorf(gy), x0f = floorf(gx);
        int   y0  = (int)y0f,   x0i = (int)x0f;
        float wy  = gy - y0f,   wx  = gx - x0f;
        int   y1  = y0 + 1,     x1i = x0i + 1;

        bool vy0 = (y0  >= 0) && (y0  < Himg);
        bool vy1 = (y1  >= 0) && (y1  < Himg);
        bool vx0 = (x0i >= 0) && (x0i < Wimg);
        bool vx1 = (x1i >= 0) && (x1i < Wimg);

        g_w00[k][pp] = (vy0 && vx0) ? (1.0f - wy) * (1.0f - wx) * mk : 0.0f;
        g_w01[k][pp] = (vy0 && vx1) ? (1.0f - wy) * wx          * mk : 0.0f;
        g_w10[k][pp] = (vy1 && vx0) ? wy          * (1.0f - wx) * mk : 0.0f;
        g_w11[k][pp] = (vy1 && vx1) ? wy          * wx          * mk : 0.0f;

        int y0c = min(max(y0, 0), Himg - 1), y1c = min(max(y1, 0), Himg - 1);
        int x0c = min(max(x0i, 0), Wimg - 1), x1c = min(max(x1i, 0), Wimg - 1);
        g_o00[k][pp]  = y0c * Wimg + x0c;
        g_pack[k][pp] = (x1c - x0c) | (((y1c - y0c) * Wimg) << 16);
    }

    float acc[4][8];
#pragma unroll
    for (int i = 0; i < 4; ++i)
#pragma unroll
        for (int j = 0; j < 8; ++j) acc[i][j] = 0.0f;

    const float* xb = x + (size_t)b * Cin * HW;

    for (int cc = 0; cc < 4; ++cc) {         // 16-channel chunk OUTER
        int c0 = cc * 16;
        for (int k = 0; k < 9; ++k) {        // tap INNER (L1 reuse)
            __syncthreads();                 // protect previous tile's readers
            // --- build V tile: 16 channels x 64 pixels ---
            float w00 = g_w00[k][p], w01 = g_w01[k][p];
            float w10 = g_w10[k][p], w11 = g_w11[k][p];
            int o00 = g_o00[k][p];
            int pk  = g_pack[k][p];
            int o01 = o00 + (pk & 0xffff);
            int o10 = o00 + (pk >> 16);
            int o11 = o10 + (pk & 0xffff);
#pragma unroll
            for (int i = 0; i < 4; ++i) {
                const float* xp = xb + (size_t)(c0 + cb + i) * HW;
                v_tile[cb + i][p] = w00 * xp[o00] + w01 * xp[o01] +
                                    w10 * xp[o10] + w11 * xp[o11];
            }
            // --- load W tile: 16 channels x 128 outputs (coalesced) ---
            const float4* wsrc = (const float4*)(wpk + (size_t)(k * Cin + c0) * OUTC);
            float4* wdst = (float4*)(&w_tile[0][0]);
            wdst[t]       = wsrc[t];
            wdst[t + 256] = wsrc[t + 256];
            __syncthreads();
            // --- accumulate 4 outs x 8 pixels over 16 channels ---
#pragma unroll
            for (int c = 0; c < 16; ++c) {
                float4 wv = *(const float4*)(&w_tile[c][og * 4]);
                float4 va = *(const float4*)(&v_tile[c][pg]);
                float4 vb = *(const float4*)(&v_tile[c][pg + 4]);
                float wv_[4] = {wv.x, wv.y, wv.z, wv.w};
                float vv_[8] = {va.x, va.y, va.z, va.w, vb.x, vb.y, vb.z, vb.w};
#pragma unroll
                for (int i = 0; i < 4; ++i)
#pragma unroll
                    for (int j = 0; j < 8; ++j)
                        acc[i][j] = fmaf(wv_[i], vv_[j], acc[i][j]);
            }
        }
    }

    // epilogue: coalesced float4 stores
#pragma unroll
    for (int i = 0; i < 4; ++i) {
        int o = og * 4 + i;
        float4 s0 = make_float4(acc[i][0], acc[i][1], acc[i][2], acc[i][3]);
        float4 s1 = make_float4(acc[i][4], acc[i][5], acc[i][6], acc[i][7]);
        float4* dst = (float4*)(out + (size_t)(b * OUTC + o) * HW + pix0 + pg);
        dst[0] = s0;
        dst[1] = s1;
    }
}

// ---------------------------------------------------------------------------
extern "C" void kernel_launch(void* const* d_in, const int* in_sizes, int n_in,
                              void* d_out, int out_size, void* d_ws, size_t ws_size,
                              hipStream_t stream) {
    const float* x        = (const float*)d_in[0];
    const float* w_offset = (const float*)d_in[1];
    const float* b_offset = (const float*)d_in[2];
    const float* w_mask   = (const float*)d_in[3];
    const float* b_mask   = (const float*)d_in[4];
    const float* w_conv   = (const float*)d_in[5];
    float* out = (float*)d_out;

    const size_t PLANE = (size_t)Bsz * Kk * HW;          // 1,179,648 floats
    float* ws    = (float*)d_ws;
    float* dy_ws = ws;
    float* dx_ws = ws + PLANE;
    float* mk_ws = ws + 2 * PLANE;
    float* wpk   = ws + 3 * PLANE;                       // 73,728 floats

    repack_w<<<288, 256, 0, stream>>>(w_conv, wpk);
    offs_mask<<<512, 256, 0, stream>>>(x, w_offset, b_offset, w_mask, b_mask,
                                       dy_ws, dx_ws, mk_ws);
    deform_gemm<<<2048, 256, 0, stream>>>(x, wpk, dy_ws, dx_ws, mk_ws, out);
}

// Round 3
// 432.596 us; speedup vs baseline: 1.2703x; 1.2703x over previous
//
#include <hip/hip_runtime.h>
#include <math.h>

#define Himg 128
#define Wimg 128
#define HW   16384      // 128*128
#define Cin  64
#define Kk   9
#define OUTC 128
#define Bsz  8

typedef __attribute__((ext_vector_type(8))) _Float16 half8;
typedef __attribute__((ext_vector_type(4))) float   floatx4;

// ---------------------------------------------------------------------------
// Kernel 0: repack w_conv[o][c][kt] (fp32) -> wpk_h[kt][cg][o][cl] (f16)
// K dim of the big GEMM is tap-major: K = kt*64 + c, chunk ch = kt*2+cg
// covers channels cg*32 .. cg*32+31.
// ---------------------------------------------------------------------------
__global__ __launch_bounds__(256) void repack_w(const float* __restrict__ w_conv,
                                                _Float16* __restrict__ wpk_h) {
    int idx = blockIdx.x * 256 + threadIdx.x;            // 0 .. 73727
    if (idx >= Kk * Cin * OUTC) return;
    int cl = idx & 31;
    int o  = (idx >> 5) & 127;
    int cg = (idx >> 12) & 1;
    int kt = idx >> 13;
    int c  = cg * 32 + cl;
    wpk_h[idx] = (_Float16)w_conv[(o * Cin + c) * 9 + kt];
}

// ---------------------------------------------------------------------------
// Kernel 1: offset conv (18 ch) + mask conv (9 ch) + sigmoid.
// Block = 2 rows x 128 cols. TWO staging phases of 32 channels each:
// stage 32ch x 4 rows (64 KB LDS) in one coalesced burst, then 32 channels
// of FMA with zero barriers. 4 barriers total (vs 128 in R2).
// ---------------------------------------------------------------------------
__global__ __launch_bounds__(256) void offs_mask(
        const float* __restrict__ x,
        const float* __restrict__ w_offset, const float* __restrict__ b_offset,
        const float* __restrict__ w_mask,   const float* __restrict__ b_mask,
        float* __restrict__ dy_out, float* __restrict__ dx_out,
        float* __restrict__ mk_out) {
    __shared__ float xs2[32][4][Wimg];     // 64 KB

    int t   = threadIdx.x;
    int bid = blockIdx.x;
    int b   = bid & 7;                     // XCD-batch swizzle
    int rp  = bid >> 3;                    // row pair 0..63
    int h0  = rp * 2;
    int hr  = t >> 7;                      // 0/1: output row h0+hr
    int w   = t & 127;
    int h   = h0 + hr;

    float acc[27];
#pragma unroll
    for (int j = 0; j < 18; ++j) acc[j] = b_offset[j];
#pragma unroll
    for (int j = 0; j < 9; ++j)  acc[18 + j] = b_mask[j];

    const float* xb = x + (size_t)b * Cin * HW;

    for (int ph = 0; ph < 2; ++ph) {
        __syncthreads();                   // protect previous phase readers
        // stage 32 channels x rows h0-1..h0+2, float4 coalesced
#pragma unroll
        for (int j = 0; j < 16; ++j) {
            int i4   = t + j * 256;        // 0..4095
            int c    = i4 >> 7;            // 0..31
            int r    = (i4 >> 5) & 3;      // 0..3
            int col4 = (i4 & 31) * 4;
            int y    = h0 - 1 + r;
            float4 v = make_float4(0.f, 0.f, 0.f, 0.f);
            if (y >= 0 && y < Himg)
                v = *(const float4*)(xb + (size_t)(ph * 32 + c) * HW + y * Wimg + col4);
            *(float4*)&xs2[c][r][col4] = v;
        }
        __syncthreads();

        for (int c = 0; c < 32; ++c) {
            float xv[9];
#pragma unroll
            for (int ty = 0; ty < 3; ++ty) {
                int r = hr + ty;
#pragma unroll
                for (int tx = 0; tx < 3; ++tx) {
                    int xx = w - 1 + tx;
                    xv[ty * 3 + tx] = (xx >= 0 && xx < Wimg) ? xs2[c][r][xx] : 0.0f;
                }
            }
            int cg = ph * 32 + c;
#pragma unroll
            for (int j = 0; j < 18; ++j) {
#pragma unroll
                for (int tp = 0; tp < 9; ++tp)
                    acc[j] = fmaf(w_offset[(j * Cin + cg) * 9 + tp], xv[tp], acc[j]);
            }
#pragma unroll
            for (int j = 0; j < 9; ++j) {
#pragma unroll
                for (int tp = 0; tp < 9; ++tp)
                    acc[18 + j] = fmaf(w_mask[(j * Cin + cg) * 9 + tp], xv[tp], acc[18 + j]);
            }
        }
    }

    int rem = h * Wimg + w;
#pragma unroll
    for (int k = 0; k < 9; ++k) {
        int idx = (b * 9 + k) * HW + rem;
        dy_out[idx] = acc[2 * k];
        dx_out[idx] = acc[2 * k + 1];
        mk_out[idx] = 1.0f / (1.0f + expf(-acc[18 + k]));
    }
}

// ---------------------------------------------------------------------------
// Kernel 2: fused deformable sampling + MFMA einsum (f16 in, fp32 acc).
// Per block: 128 outs x 64 pixels, K=576 tap-major in 18 chunks of 32.
// Per chunk: all 256 threads build V (64px x 32ch, f16, [px][k] layout,
// rows padded to 40 halves = 80 B) + stage W tile (128 x 32 f16), then each
// of 4 waves does 8x mfma_f32_16x16x32_f16 (2 m-tiles x 4 n-tiles).
// Fragment layouts (guide §3, HW-verified): A[m=lane&15][k=(lane>>4)*8+j],
// B[k=(lane>>4)*8+j][n=lane&15], D: col=lane&15, row=(lane>>4)*4+reg.
// ---------------------------------------------------------------------------
#define PPB 64
__global__ __launch_bounds__(256) void deform_gemm(
        const float* __restrict__ x, const _Float16* __restrict__ wpk_h,
        const float* __restrict__ dy_ws, const float* __restrict__ dx_ws,
        const float* __restrict__ mk_ws, float* __restrict__ out) {
    __shared__ _Float16 Vlds[PPB][40];       // 5.0 KB (pad 40: 80 B rows)
    __shared__ _Float16 Wlds[OUTC][40];      // 10.0 KB
    __shared__ float g_w00[Kk][PPB], g_w01[Kk][PPB];
    __shared__ float g_w10[Kk][PPB], g_w11[Kk][PPB];
    __shared__ int   g_o00[Kk][PPB];
    __shared__ int   g_pack[Kk][PPB];        // dx1 | (dyrow<<16)

    int t    = threadIdx.x;
    int bid  = blockIdx.x;
    int b    = bid & 7;                      // XCD-batch swizzle
    int pb   = bid >> 3;                     // 0..255
    int pix0 = pb * PPB;
    int h    = pix0 >> 7;                    // row (fixed per block)
    int w0   = pix0 & 127;                   // 0 or 64

    int lane = t & 63;
    int wv   = t >> 6;                       // wave id 0..3
    int p    = t & 63;                       // sampler: pixel
    int cb   = (t >> 6) * 8;                 // sampler: 8-ch sub-base in chunk
    int m0   = wv * 32;                      // mfma: wave's output base
    int kq   = lane >> 4;                    // frag quad
    int ln16 = lane & 15;

    // ---- geometry precompute: 576 items, once ----
    for (int it = t; it < Kk * PPB; it += 256) {
        int k  = it >> 6;
        int pp = it & 63;
        int sidx = (b * 9 + k) * HW + pix0 + pp;
        float dy = dy_ws[sidx];
        float dx = dx_ws[sidx];
        float mk = mk_ws[sidx];

        float gy  = (float)h + (float)(k / 3) - 1.0f + dy;
        float gx  = (float)(w0 + pp) + (float)(k % 3) - 1.0f + dx;
        float y0f = floorf(gy), x0f = floorf(gx);
        int   y0  = (int)y0f,   x0i = (int)x0f;
        float wy  = gy - y0f,   wx  = gx - x0f;
        int   y1  = y0 + 1,     x1i = x0i + 1;

        bool vy0 = (y0  >= 0) && (y0  < Himg);
        bool vy1 = (y1  >= 0) && (y1  < Himg);
        bool vx0 = (x0i >= 0) && (x0i < Wimg);
        bool vx1 = (x1i >= 0) && (x1i < Wimg);

        g_w00[k][pp] = (vy0 && vx0) ? (1.0f - wy) * (1.0f - wx) * mk : 0.0f;
        g_w01[k][pp] = (vy0 && vx1) ? (1.0f - wy) * wx          * mk : 0.0f;
        g_w10[k][pp] = (vy1 && vx0) ? wy          * (1.0f - wx) * mk : 0.0f;
        g_w11[k][pp] = (vy1 && vx1) ? wy          * wx          * mk : 0.0f;

        int y0c = min(max(y0, 0), Himg - 1), y1c = min(max(y1, 0), Himg - 1);
        int x0c = min(max(x0i, 0), Wimg - 1), x1c = min(max(x1i, 0), Wimg - 1);
        g_o00[k][pp]  = y0c * Wimg + x0c;
        g_pack[k][pp] = (x1c - x0c) | (((y1c - y0c) * Wimg) << 16);
    }

    floatx4 acc[2][4];
#pragma unroll
    for (int i = 0; i < 2; ++i)
#pragma unroll
        for (int j = 0; j < 4; ++j) acc[i][j] = (floatx4){0.f, 0.f, 0.f, 0.f};

    const float* xb = x + (size_t)b * Cin * HW;

    for (int ch = 0; ch < 18; ++ch) {        // K chunk = (tap, ch-half)
        int kt = ch >> 1;
        int cg = ch & 1;
        __syncthreads();                     // protect prev tile readers
                                             // (also orders geometry writes)
        // --- build V tile: 64 px x 32 ch, f16, [px][k_local] ---
        float w00 = g_w00[kt][p], w01 = g_w01[kt][p];
        float w10 = g_w10[kt][p], w11 = g_w11[kt][p];
        int o00 = g_o00[kt][p];
        int pk  = g_pack[kt][p];
        int o01 = o00 + (pk & 0xffff);
        int o10 = o00 + (pk >> 16);
        int o11 = o10 + (pk & 0xffff);

        half8 vv;
        const float* xpc = xb + (size_t)(cg * 32 + cb) * HW;
#pragma unroll
        for (int i = 0; i < 8; ++i) {
            const float* xp = xpc + (size_t)i * HW;
            float v = w00 * xp[o00] + w01 * xp[o01] +
                      w10 * xp[o10] + w11 * xp[o11];
            vv[i] = (_Float16)v;
        }
        *(half8*)&Vlds[p][cb] = vv;

        // --- stage W tile: 128 outs x 32 k (f16, contiguous in global) ---
        const half8* wsrc = (const half8*)(wpk_h + (size_t)ch * (OUTC * 32));
        half8 wa = wsrc[2 * t];
        half8 wb = wsrc[2 * t + 1];
        int oo  = t >> 1;
        int cl0 = (t & 1) * 16;
        *(half8*)&Wlds[oo][cl0]     = wa;
        *(half8*)&Wlds[oo][cl0 + 8] = wb;
        __syncthreads();

        // --- MFMA: 2 m-tiles x 4 n-tiles ---
        half8 a0 = *(const half8*)&Wlds[m0 + ln16][kq * 8];
        half8 a1 = *(const half8*)&Wlds[m0 + 16 + ln16][kq * 8];
#pragma unroll
        for (int nt = 0; nt < 4; ++nt) {
            half8 bf = *(const half8*)&Vlds[nt * 16 + ln16][kq * 8];
            acc[0][nt] = __builtin_amdgcn_mfma_f32_16x16x32_f16(a0, bf, acc[0][nt], 0, 0, 0);
            acc[1][nt] = __builtin_amdgcn_mfma_f32_16x16x32_f16(a1, bf, acc[1][nt], 0, 0, 0);
        }
    }

    // epilogue: D col=lane&15 (pixel), row=(lane>>4)*4+reg (output)
#pragma unroll
    for (int mt = 0; mt < 2; ++mt) {
#pragma unroll
        for (int nt = 0; nt < 4; ++nt) {
#pragma unroll
            for (int r = 0; r < 4; ++r) {
                int o  = m0 + mt * 16 + kq * 4 + r;
                int px = nt * 16 + ln16;
                out[(size_t)(b * OUTC + o) * HW + pix0 + px] = acc[mt][nt][r];
            }
        }
    }
}

// ---------------------------------------------------------------------------
extern "C" void kernel_launch(void* const* d_in, const int* in_sizes, int n_in,
                              void* d_out, int out_size, void* d_ws, size_t ws_size,
                              hipStream_t stream) {
    const float* x        = (const float*)d_in[0];
    const float* w_offset = (const float*)d_in[1];
    const float* b_offset = (const float*)d_in[2];
    const float* w_mask   = (const float*)d_in[3];
    const float* b_mask   = (const float*)d_in[4];
    const float* w_conv   = (const float*)d_in[5];
    float* out = (float*)d_out;

    const size_t PLANE = (size_t)Bsz * Kk * HW;          // 1,179,648 floats
    float* ws    = (float*)d_ws;
    float* dy_ws = ws;
    float* dx_ws = ws + PLANE;
    float* mk_ws = ws + 2 * PLANE;
    _Float16* wpk_h = (_Float16*)(ws + 3 * PLANE);       // 73,728 halves

    repack_w<<<288, 256, 0, stream>>>(w_conv, wpk_h);
    offs_mask<<<512, 256, 0, stream>>>(x, w_offset, b_offset, w_mask, b_mask,
                                       dy_ws, dx_ws, mk_ws);
    deform_gemm<<<2048, 256, 0, stream>>>(x, wpk_h, dy_ws, dx_ws, mk_ws, out);
}

// Round 5
// 416.728 us; speedup vs baseline: 1.3187x; 1.0381x over previous
//
#include <hip/hip_runtime.h>
#include <math.h>

#define Himg 128
#define Wimg 128
#define HW   16384      // 128*128
#define Cin  64
#define Kk   9
#define OUTC 128
#define Bsz  8

typedef __attribute__((ext_vector_type(8))) _Float16 half8;
typedef __attribute__((ext_vector_type(4))) float   floatx4;

// ---------------------------------------------------------------------------
// repack main conv weights: wpk_h[ch][o][kl], ch = kt*2+cg, kl = c - cg*32
// ---------------------------------------------------------------------------
__global__ __launch_bounds__(256) void repack_w(const float* __restrict__ w_conv,
                                                _Float16* __restrict__ wpk_h) {
    int idx = blockIdx.x * 256 + threadIdx.x;            // 0 .. 73727
    if (idx >= Kk * Cin * OUTC) return;
    int cl = idx & 31;
    int o  = (idx >> 5) & 127;
    int cg = (idx >> 12) & 1;
    int kt = idx >> 13;
    int c  = cg * 32 + cl;
    wpk_h[idx] = (_Float16)w_conv[(o * Cin + c) * 9 + kt];
}

// ---------------------------------------------------------------------------
// repack offset+mask weights: wpk2[ch][m][kl] (f16), m: 0..17 offset chans,
// 18..26 mask chans, 27..31 zero pad.
// ---------------------------------------------------------------------------
__global__ __launch_bounds__(256) void repack_w2(const float* __restrict__ w_offset,
                                                 const float* __restrict__ w_mask,
                                                 _Float16* __restrict__ wpk2) {
    int idx = blockIdx.x * 256 + threadIdx.x;            // 0 .. 18431
    if (idx >= 18 * 32 * 32) return;
    int kl = idx & 31;
    int m  = (idx >> 5) & 31;
    int ch = idx >> 10;
    int kt = ch >> 1;
    int c  = (ch & 1) * 32 + kl;
    float v = 0.0f;
    if (m < 18)      v = w_offset[(m * Cin + c) * 9 + kt];
    else if (m < 27) v = w_mask[((m - 18) * Cin + c) * 9 + kt];
    wpk2[idx] = (_Float16)v;
}

// ---------------------------------------------------------------------------
// Fused kernel. Phase 0: offset/mask conv via MFMA -> P in LDS -> geometry
// in registers (R3's VERIFIED 4-corner clamped-gather scheme, weights
// f16-pair-packed). Phase 1: sampling + MFMA einsum, V/W double-buffered,
// one barrier per chunk, next chunk's 4x8 scalar gathers (4B-aligned dword
// loads ONLY — R4's misaligned float2 pair-loads removed) + W tile
// prefetched into registers before the barrier.
// ---------------------------------------------------------------------------
__global__ __launch_bounds__(256, 3) void deform_fused(
        const float* __restrict__ x, const _Float16* __restrict__ wpk_h,
        const _Float16* __restrict__ wpk2,
        const float* __restrict__ b_offset, const float* __restrict__ b_mask,
        float* __restrict__ out) {
    __shared__ union SMem {
        struct { _Float16 V0[64][40]; _Float16 W2[32][40]; float P[32][66]; } p0;
        struct { _Float16 V[2][64][40]; _Float16 Wt[2][128][40]; } p1;  // 30 KB
    } sm;

    int t    = threadIdx.x;
    int bid  = blockIdx.x;
    int b    = bid & 7;                      // XCD-batch swizzle
    int pb   = bid >> 3;                     // 0..255
    int pix0 = pb * 64;
    int h    = pix0 >> 7;
    int w0   = pix0 & 127;                   // 0 or 64

    int lane = t & 63;
    int wv   = t >> 6;
    int p    = lane;                         // sampler pixel
    int cb   = wv * 8;                       // sampler channel sub-base
    int kq   = lane >> 4;
    int ln16 = lane & 15;

    const float* xb = x + (size_t)b * Cin * HW;

    // ================= phase 0: offset/mask conv =================
    floatx4 acc2[2];
    acc2[0] = (floatx4){0.f, 0.f, 0.f, 0.f};
    acc2[1] = (floatx4){0.f, 0.f, 0.f, 0.f};
    int mt0 = wv & 1;                        // wave's m-tile
    int ntA = wv >> 1;                       // wave's n-tiles: ntA, ntA+2

    for (int ch = 0; ch < 18; ++ch) {
        int kt = ch >> 1, cg = ch & 1;
        int row = h + (kt / 3) - 1;
        int col = w0 + p + (kt % 3) - 1;
        bool okc = (row >= 0) && (row < Himg) && (col >= 0) && (col < Wimg);
        const float* xpc = xb + (size_t)(cg * 32 + cb) * HW + row * Wimg + col;
        __syncthreads();
        half8 vv;
#pragma unroll
        for (int i = 0; i < 8; ++i)
            vv[i] = okc ? (_Float16)xpc[(size_t)i * HW] : (_Float16)0.f;
        *(half8*)&sm.p0.V0[p][cb] = vv;
        if (t < 128) {
            const half8* wsrc = (const half8*)(wpk2 + (size_t)ch * 1024);
            half8 wq = wsrc[t];
            *(half8*)&sm.p0.W2[t >> 2][(t & 3) * 8] = wq;
        }
        __syncthreads();
        half8 af = *(const half8*)&sm.p0.W2[mt0 * 16 + ln16][kq * 8];
        half8 b0 = *(const half8*)&sm.p0.V0[ntA * 16 + ln16][kq * 8];
        half8 b1 = *(const half8*)&sm.p0.V0[(ntA + 2) * 16 + ln16][kq * 8];
        acc2[0] = __builtin_amdgcn_mfma_f32_16x16x32_f16(af, b0, acc2[0], 0, 0, 0);
        acc2[1] = __builtin_amdgcn_mfma_f32_16x16x32_f16(af, b1, acc2[1], 0, 0, 0);
    }
    __syncthreads();
    // write P (27 used rows x 64 px, fp32)
#pragma unroll
    for (int j = 0; j < 2; ++j) {
        int nt = ntA + 2 * j;
#pragma unroll
        for (int r = 0; r < 4; ++r)
            sm.p0.P[mt0 * 16 + kq * 4 + r][nt * 16 + ln16] = acc2[j][r];
    }
    __syncthreads();

    // ---- per-pixel geometry -> registers (R3's verified 4-corner form) ----
    int      o00r[9], packr[9];
    unsigned wab[9], wcd[9];                 // f16-packed (w00,w01),(w10,w11)
    {
        float fh = (float)h, fw = (float)(w0 + p);
#pragma unroll
        for (int k = 0; k < 9; ++k) {
            float dyv = sm.p0.P[2 * k][p]     + b_offset[2 * k];
            float dxv = sm.p0.P[2 * k + 1][p] + b_offset[2 * k + 1];
            float mz  = sm.p0.P[18 + k][p]    + b_mask[k];
            float mkv = 1.0f / (1.0f + expf(-mz));

            float gy  = fh + (float)(k / 3) - 1.0f + dyv;
            float gx  = fw + (float)(k % 3) - 1.0f + dxv;
            float y0f = floorf(gy), x0f = floorf(gx);
            int   y0  = (int)y0f,   x0 = (int)x0f;
            float wy  = gy - y0f,   wx = gx - x0f;
            int   y1  = y0 + 1,     x1 = x0 + 1;

            bool vy0 = (y0 >= 0) && (y0 < Himg);
            bool vy1 = (y1 >= 0) && (y1 < Himg);
            bool vx0 = (x0 >= 0) && (x0 < Wimg);
            bool vx1 = (x1 >= 0) && (x1 < Wimg);

            float w00 = (vy0 && vx0) ? (1.0f - wy) * (1.0f - wx) * mkv : 0.0f;
            float w01 = (vy0 && vx1) ? (1.0f - wy) * wx          * mkv : 0.0f;
            float w10 = (vy1 && vx0) ? wy          * (1.0f - wx) * mkv : 0.0f;
            float w11 = (vy1 && vx1) ? wy          * wx          * mkv : 0.0f;

            int y0c = min(max(y0, 0), Himg - 1), y1c = min(max(y1, 0), Himg - 1);
            int x0c = min(max(x0, 0), Wimg - 1), x1c = min(max(x1, 0), Wimg - 1);
            o00r[k]  = y0c * Wimg + x0c;
            packr[k] = (x1c - x0c) | (((y1c - y0c) * Wimg) << 16);
            union { unsigned u; _Float16 hh[2]; } pk;
            pk.hh[0] = (_Float16)w00; pk.hh[1] = (_Float16)w01; wab[k] = pk.u;
            pk.hh[0] = (_Float16)w10; pk.hh[1] = (_Float16)w11; wcd[k] = pk.u;
        }
    }

    // ================= phase 1: deformable sampling + GEMM =================
    floatx4 acc[2][4];
#pragma unroll
    for (int i = 0; i < 2; ++i)
#pragma unroll
        for (int j = 0; j < 4; ++j) acc[i][j] = (floatx4){0.f, 0.f, 0.f, 0.f};
    int m0 = wv * 32;

    float ga[8], gb[8], gc[8], gd[8];
    half8 wa, wb;
    // prefetch chunk 0 (register-only; before the union-transition sync)
    {
        int o00 = o00r[0], pk = packr[0];
        int o01 = o00 + (pk & 0xffff);
        int o10 = o00 + (pk >> 16);
        int o11 = o10 + (pk & 0xffff);
        const float* xpc = xb + (size_t)cb * HW;
#pragma unroll
        for (int i = 0; i < 8; ++i) {
            const float* xp = xpc + (size_t)i * HW;
            ga[i] = xp[o00]; gb[i] = xp[o01];
            gc[i] = xp[o10]; gd[i] = xp[o11];
        }
        const half8* wsrc = (const half8*)wpk_h;
        wa = wsrc[2 * t];
        wb = wsrc[2 * t + 1];
    }
    __syncthreads();                       // P dead; p1 buffers live

    for (int ch = 0; ch < 18; ++ch) {
        int kt  = ch >> 1;
        int buf = ch & 1;
        // combine current chunk's gathers -> V f16
        union { unsigned u; _Float16 hh[2]; } u1, u2;
        u1.u = wab[kt];  u2.u = wcd[kt];
        float w00 = (float)u1.hh[0], w01 = (float)u1.hh[1];
        float w10 = (float)u2.hh[0], w11 = (float)u2.hh[1];
        half8 vv;
#pragma unroll
        for (int i = 0; i < 8; ++i) {
            float v = w00 * ga[i] + w01 * gb[i] + w10 * gc[i] + w11 * gd[i];
            vv[i] = (_Float16)v;
        }
        *(half8*)&sm.p1.V[buf][p][cb] = vv;
        {   // W tile from prefetched regs
            int oo = t >> 1, cl0 = (t & 1) * 16;
            *(half8*)&sm.p1.Wt[buf][oo][cl0]     = wa;
            *(half8*)&sm.p1.Wt[buf][oo][cl0 + 8] = wb;
        }
        // issue NEXT chunk's loads (stay in flight across the barrier)
        if (ch < 17) {
            int chn = ch + 1, ktn = chn >> 1, cgn = chn & 1;
            int o00 = o00r[ktn], pk = packr[ktn];
            int o01 = o00 + (pk & 0xffff);
            int o10 = o00 + (pk >> 16);
            int o11 = o10 + (pk & 0xffff);
            const float* xpc = xb + (size_t)(cgn * 32 + cb) * HW;
#pragma unroll
            for (int i = 0; i < 8; ++i) {
                const float* xp = xpc + (size_t)i * HW;
                ga[i] = xp[o00]; gb[i] = xp[o01];
                gc[i] = xp[o10]; gd[i] = xp[o11];
            }
            const half8* wsrc = (const half8*)(wpk_h + (size_t)chn * 4096);
            wa = wsrc[2 * t];
            wb = wsrc[2 * t + 1];
        }
        __syncthreads();
        // MFMA: 2 m-tiles x 4 n-tiles
        half8 a0 = *(const half8*)&sm.p1.Wt[buf][m0 + ln16][kq * 8];
        half8 a1 = *(const half8*)&sm.p1.Wt[buf][m0 + 16 + ln16][kq * 8];
#pragma unroll
        for (int nt = 0; nt < 4; ++nt) {
            half8 bf = *(const half8*)&sm.p1.V[buf][nt * 16 + ln16][kq * 8];
            acc[0][nt] = __builtin_amdgcn_mfma_f32_16x16x32_f16(a0, bf, acc[0][nt], 0, 0, 0);
            acc[1][nt] = __builtin_amdgcn_mfma_f32_16x16x32_f16(a1, bf, acc[1][nt], 0, 0, 0);
        }
    }

    // epilogue: D col=lane&15 (pixel), row=(lane>>4)*4+reg (output)
#pragma unroll
    for (int mtl = 0; mtl < 2; ++mtl) {
#pragma unroll
        for (int nt = 0; nt < 4; ++nt) {
#pragma unroll
            for (int r = 0; r < 4; ++r) {
                int o  = m0 + mtl * 16 + kq * 4 + r;
                int px = nt * 16 + ln16;
                out[(size_t)(b * OUTC + o) * HW + pix0 + px] = acc[mtl][nt][r];
            }
        }
    }
}

// ---------------------------------------------------------------------------
extern "C" void kernel_launch(void* const* d_in, const int* in_sizes, int n_in,
                              void* d_out, int out_size, void* d_ws, size_t ws_size,
                              hipStream_t stream) {
    const float* x        = (const float*)d_in[0];
    const float* w_offset = (const float*)d_in[1];
    const float* b_offset = (const float*)d_in[2];
    const float* w_mask   = (const float*)d_in[3];
    const float* b_mask   = (const float*)d_in[4];
    const float* w_conv   = (const float*)d_in[5];
    float* out = (float*)d_out;

    _Float16* wpk_h = (_Float16*)d_ws;                   // 73,728 halves
    _Float16* wpk2  = wpk_h + 73728;                     // 18,432 halves

    repack_w<<<288, 256, 0, stream>>>(w_conv, wpk_h);
    repack_w2<<<72, 256, 0, stream>>>(w_offset, w_mask, wpk2);
    deform_fused<<<2048, 256, 0, stream>>>(x, wpk_h, wpk2, b_offset, b_mask, out);
}

// Round 6
// 235.998 us; speedup vs baseline: 2.3286x; 1.7658x over previous
//
#include <hip/hip_runtime.h>
#include <math.h>

#define Himg 128
#define Wimg 128
#define HW   16384      // 128*128
#define Cin  64
#define Kk   9
#define OUTC 128
#define Bsz  8

typedef __attribute__((ext_vector_type(8))) _Float16 half8;
typedef __attribute__((ext_vector_type(4))) float   floatx4;

// ---------------------------------------------------------------------------
// transpose+convert: x[b][c][h][w] f32 -> xt[b][h][w][c] f16
// one block per (b,h) row; LDS tile 64ch x 128w (pad 130 -> 2-way-max banks)
// ---------------------------------------------------------------------------
__global__ __launch_bounds__(256) void transpose_x(const float* __restrict__ x,
                                                   _Float16* __restrict__ xt) {
    __shared__ _Float16 tile[Cin][130];
    int t   = threadIdx.x;
    int bid = blockIdx.x;            // 0..1023
    int b   = bid >> 7;
    int h   = bid & 127;
    const float* xb = x + (size_t)b * Cin * HW + (size_t)h * Wimg;
#pragma unroll
    for (int j = 0; j < 32; ++j) {
        int e = t + j * 256;         // 0..8191
        int c = e >> 7;
        int w = e & 127;
        tile[c][w] = (_Float16)xb[(size_t)c * HW + w];
    }
    __syncthreads();
    unsigned* dst = (unsigned*)xt + ((size_t)b * HW + (size_t)h * Wimg) * 32;
#pragma unroll
    for (int j = 0; j < 16; ++j) {
        int d  = t + j * 256;        // 0..4095
        int w  = d >> 5;
        int cp = d & 31;
        union { unsigned u; _Float16 hh[2]; } pk;
        pk.hh[0] = tile[2 * cp][w];
        pk.hh[1] = tile[2 * cp + 1][w];
        dst[d] = pk.u;
    }
}

// ---------------------------------------------------------------------------
// repack main conv weights: wpk_h[ch][o][kl], ch = kt*2+cg, kl = c - cg*32
// ---------------------------------------------------------------------------
__global__ __launch_bounds__(256) void repack_w(const float* __restrict__ w_conv,
                                                _Float16* __restrict__ wpk_h) {
    int idx = blockIdx.x * 256 + threadIdx.x;            // 0 .. 73727
    if (idx >= Kk * Cin * OUTC) return;
    int cl = idx & 31;
    int o  = (idx >> 5) & 127;
    int cg = (idx >> 12) & 1;
    int kt = idx >> 13;
    int c  = cg * 32 + cl;
    wpk_h[idx] = (_Float16)w_conv[(o * Cin + c) * 9 + kt];
}

// ---------------------------------------------------------------------------
// repack offset+mask weights: wpk2[ch][m][kl] (f16), m: 0..17 offset chans,
// 18..26 mask chans, 27..31 zero pad.
// ---------------------------------------------------------------------------
__global__ __launch_bounds__(256) void repack_w2(const float* __restrict__ w_offset,
                                                 const float* __restrict__ w_mask,
                                                 _Float16* __restrict__ wpk2) {
    int idx = blockIdx.x * 256 + threadIdx.x;            // 0 .. 18431
    if (idx >= 18 * 32 * 32) return;
    int kl = idx & 31;
    int m  = (idx >> 5) & 31;
    int ch = idx >> 10;
    int kt = ch >> 1;
    int c  = (ch & 1) * 32 + kl;
    float v = 0.0f;
    if (m < 18)      v = w_offset[(m * Cin + c) * 9 + kt];
    else if (m < 27) v = w_mask[((m - 18) * Cin + c) * 9 + kt];
    wpk2[idx] = (_Float16)v;
}

// ---------------------------------------------------------------------------
// Fused kernel, channel-last f16 x (xt). Phase 0: offset/mask conv via MFMA
// (single-barrier double-buffered). Geometry in registers (loops fully
// unrolled -> no scratch). Phase 1: per chunk each thread gathers its 8
// channels per bilinear corner with ONE aligned dwordx4 (4 loads/chunk vs 32
// scalar) -> V f16 -> double-buffered MFMA, one barrier per chunk, next
// chunk's gathers + W tile prefetched into registers before the barrier.
// ---------------------------------------------------------------------------
__global__ __launch_bounds__(256, 3) void deform_fused(
        const _Float16* __restrict__ xt, const _Float16* __restrict__ wpk_h,
        const _Float16* __restrict__ wpk2,
        const float* __restrict__ b_offset, const float* __restrict__ b_mask,
        float* __restrict__ out) {
    __shared__ union SMem {
        struct { _Float16 V0[2][64][40]; _Float16 W2[2][32][40]; float P[32][66]; } p0;
        struct { _Float16 V[2][64][40]; _Float16 Wt[2][128][40]; } p1;  // 30 KB
    } sm;

    int t    = threadIdx.x;
    int bid  = blockIdx.x;
    int b    = bid & 7;                      // XCD-batch swizzle
    int pb   = bid >> 3;                     // 0..255
    int pix0 = pb * 64;
    int h    = pix0 >> 7;
    int w0   = pix0 & 127;                   // 0 or 64

    int lane = t & 63;
    int wv   = t >> 6;
    int p    = lane;                         // sampler pixel
    int cb   = wv * 8;                       // sampler channel sub-base
    int kq   = lane >> 4;
    int ln16 = lane & 15;

    const _Float16* xtb = xt + (size_t)b * HW * Cin;

    // ================= phase 0: offset/mask conv =================
    floatx4 acc2[2];
    acc2[0] = (floatx4){0.f, 0.f, 0.f, 0.f};
    acc2[1] = (floatx4){0.f, 0.f, 0.f, 0.f};
    int mt0 = wv & 1;                        // wave's m-tile
    int ntA = wv >> 1;                       // wave's n-tiles: ntA, ntA+2

    half8 pv, pw;
    {   // prefetch chunk 0 (kt=0: row=h-1, col=w0+p-1, cg=0)
        int row = h - 1, col = w0 + p - 1;
        bool okc = (row >= 0) && (col >= 0) && (col < Wimg);
        if (okc) pv = *(const half8*)(xtb + ((size_t)(row * Wimg + col)) * Cin + cb);
        else {
#pragma unroll
            for (int i = 0; i < 8; ++i) pv[i] = (_Float16)0.f;
        }
        if (t < 128) pw = ((const half8*)wpk2)[t];
    }

#pragma unroll
    for (int ch = 0; ch < 18; ++ch) {
        int buf = ch & 1;
        *(half8*)&sm.p0.V0[buf][p][cb] = pv;
        if (t < 128) *(half8*)&sm.p0.W2[buf][t >> 2][(t & 3) * 8] = pw;
        if (ch < 17) {
            int chn = ch + 1, ktn = chn >> 1, cgn = chn & 1;
            int row = h + (ktn / 3) - 1;
            int col = w0 + p + (ktn % 3) - 1;
            bool okc = (row >= 0) && (row < Himg) && (col >= 0) && (col < Wimg);
            if (okc) pv = *(const half8*)(xtb + ((size_t)(row * Wimg + col)) * Cin
                                          + cgn * 32 + cb);
            else {
#pragma unroll
                for (int i = 0; i < 8; ++i) pv[i] = (_Float16)0.f;
            }
            if (t < 128) pw = ((const half8*)(wpk2 + (size_t)chn * 1024))[t];
        }
        __syncthreads();
        half8 af = *(const half8*)&sm.p0.W2[buf][mt0 * 16 + ln16][kq * 8];
        half8 b0 = *(const half8*)&sm.p0.V0[buf][ntA * 16 + ln16][kq * 8];
        half8 b1 = *(const half8*)&sm.p0.V0[buf][(ntA + 2) * 16 + ln16][kq * 8];
        acc2[0] = __builtin_amdgcn_mfma_f32_16x16x32_f16(af, b0, acc2[0], 0, 0, 0);
        acc2[1] = __builtin_amdgcn_mfma_f32_16x16x32_f16(af, b1, acc2[1], 0, 0, 0);
    }
    // write P (27 used rows x 64 px, fp32) — P disjoint from V0/W2, no race
#pragma unroll
    for (int j = 0; j < 2; ++j) {
        int nt = ntA + 2 * j;
#pragma unroll
        for (int r = 0; r < 4; ++r)
            sm.p0.P[mt0 * 16 + kq * 4 + r][nt * 16 + ln16] = acc2[j][r];
    }
    __syncthreads();

    // ---- per-pixel geometry -> registers (verified 4-corner form) ----
    int      o00r[9], packr[9];
    unsigned wab[9], wcd[9];                 // f16-packed (w00,w01),(w10,w11)
    {
        float fh = (float)h, fw = (float)(w0 + p);
#pragma unroll
        for (int k = 0; k < 9; ++k) {
            float dyv = sm.p0.P[2 * k][p]     + b_offset[2 * k];
            float dxv = sm.p0.P[2 * k + 1][p] + b_offset[2 * k + 1];
            float mz  = sm.p0.P[18 + k][p]    + b_mask[k];
            float mkv = 1.0f / (1.0f + expf(-mz));

            float gy  = fh + (float)(k / 3) - 1.0f + dyv;
            float gx  = fw + (float)(k % 3) - 1.0f + dxv;
            float y0f = floorf(gy), x0f = floorf(gx);
            int   y0  = (int)y0f,   x0 = (int)x0f;
            float wy  = gy - y0f,   wx = gx - x0f;
            int   y1  = y0 + 1,     x1 = x0 + 1;

            bool vy0 = (y0 >= 0) && (y0 < Himg);
            bool vy1 = (y1 >= 0) && (y1 < Himg);
            bool vx0 = (x0 >= 0) && (x0 < Wimg);
            bool vx1 = (x1 >= 0) && (x1 < Wimg);

            float w00 = (vy0 && vx0) ? (1.0f - wy) * (1.0f - wx) * mkv : 0.0f;
            float w01 = (vy0 && vx1) ? (1.0f - wy) * wx          * mkv : 0.0f;
            float w10 = (vy1 && vx0) ? wy          * (1.0f - wx) * mkv : 0.0f;
            float w11 = (vy1 && vx1) ? wy          * wx          * mkv : 0.0f;

            int y0c = min(max(y0, 0), Himg - 1), y1c = min(max(y1, 0), Himg - 1);
            int x0c = min(max(x0, 0), Wimg - 1), x1c = min(max(x1, 0), Wimg - 1);
            o00r[k]  = y0c * Wimg + x0c;                       // CELL index
            packr[k] = (x1c - x0c) | ((y1c - y0c) << 16);
            union { unsigned u; _Float16 hh[2]; } pk;
            pk.hh[0] = (_Float16)w00; pk.hh[1] = (_Float16)w01; wab[k] = pk.u;
            pk.hh[0] = (_Float16)w10; pk.hh[1] = (_Float16)w11; wcd[k] = pk.u;
        }
    }

    // ================= phase 1: deformable sampling + GEMM =================
    floatx4 acc[2][4];
#pragma unroll
    for (int i = 0; i < 2; ++i)
#pragma unroll
        for (int j = 0; j < 4; ++j) acc[i][j] = (floatx4){0.f, 0.f, 0.f, 0.f};
    int m0 = wv * 32;

    half8 ga, gb, gc, gd, wa, wb;
    {   // prefetch chunk 0 (register-only; before the union-transition sync)
        int o00 = o00r[0], pk = packr[0];
        const _Float16* xc = xtb + (size_t)o00 * Cin + cb;   // cg=0
        int ob = (pk & 0xffff) << 6;                         // dx1 * 64
        int oc = (pk >> 16) << 13;                           // dyr * 8192
        ga = *(const half8*)(xc);
        gb = *(const half8*)(xc + ob);
        gc = *(const half8*)(xc + oc);
        gd = *(const half8*)(xc + oc + ob);
        const half8* wsrc = (const half8*)wpk_h;
        wa = wsrc[2 * t];
        wb = wsrc[2 * t + 1];
    }
    __syncthreads();                       // P dead; p1 buffers live

#pragma unroll
    for (int ch = 0; ch < 18; ++ch) {
        int kt  = ch >> 1;
        int buf = ch & 1;
        // combine current chunk's gathers -> V f16
        union { unsigned u; _Float16 hh[2]; } u1, u2;
        u1.u = wab[kt];  u2.u = wcd[kt];
        float w00 = (float)u1.hh[0], w01 = (float)u1.hh[1];
        float w10 = (float)u2.hh[0], w11 = (float)u2.hh[1];
        half8 vv;
#pragma unroll
        for (int i = 0; i < 8; ++i) {
            float v = w00 * (float)ga[i] + w01 * (float)gb[i] +
                      w10 * (float)gc[i] + w11 * (float)gd[i];
            vv[i] = (_Float16)v;
        }
        *(half8*)&sm.p1.V[buf][p][cb] = vv;
        {   // W tile from prefetched regs
            int oo = t >> 1, cl0 = (t & 1) * 16;
            *(half8*)&sm.p1.Wt[buf][oo][cl0]     = wa;
            *(half8*)&sm.p1.Wt[buf][oo][cl0 + 8] = wb;
        }
        // issue NEXT chunk's loads (stay in flight across the barrier)
        if (ch < 17) {
            int chn = ch + 1, ktn = chn >> 1, cgn = chn & 1;
            int o00 = o00r[ktn], pk = packr[ktn];
            const _Float16* xc = xtb + (size_t)o00 * Cin + cgn * 32 + cb;
            int ob = (pk & 0xffff) << 6;
            int oc = (pk >> 16) << 13;
            ga = *(const half8*)(xc);
            gb = *(const half8*)(xc + ob);
            gc = *(const half8*)(xc + oc);
            gd = *(const half8*)(xc + oc + ob);
            const half8* wsrc = (const half8*)(wpk_h + (size_t)chn * 4096);
            wa = wsrc[2 * t];
            wb = wsrc[2 * t + 1];
        }
        __syncthreads();
        // MFMA: 2 m-tiles x 4 n-tiles
        half8 a0 = *(const half8*)&sm.p1.Wt[buf][m0 + ln16][kq * 8];
        half8 a1 = *(const half8*)&sm.p1.Wt[buf][m0 + 16 + ln16][kq * 8];
#pragma unroll
        for (int nt = 0; nt < 4; ++nt) {
            half8 bf = *(const half8*)&sm.p1.V[buf][nt * 16 + ln16][kq * 8];
            acc[0][nt] = __builtin_amdgcn_mfma_f32_16x16x32_f16(a0, bf, acc[0][nt], 0, 0, 0);
            acc[1][nt] = __builtin_amdgcn_mfma_f32_16x16x32_f16(a1, bf, acc[1][nt], 0, 0, 0);
        }
    }

    // epilogue: D col=lane&15 (pixel), row=(lane>>4)*4+reg (output)
#pragma unroll
    for (int mtl = 0; mtl < 2; ++mtl) {
#pragma unroll
        for (int nt = 0; nt < 4; ++nt) {
#pragma unroll
            for (int r = 0; r < 4; ++r) {
                int o  = m0 + mtl * 16 + kq * 4 + r;
                int px = nt * 16 + ln16;
                out[(size_t)(b * OUTC + o) * HW + pix0 + px] = acc[mtl][nt][r];
            }
        }
    }
}

// ---------------------------------------------------------------------------
extern "C" void kernel_launch(void* const* d_in, const int* in_sizes, int n_in,
                              void* d_out, int out_size, void* d_ws, size_t ws_size,
                              hipStream_t stream) {
    const float* x        = (const float*)d_in[0];
    const float* w_offset = (const float*)d_in[1];
    const float* b_offset = (const float*)d_in[2];
    const float* w_mask   = (const float*)d_in[3];
    const float* b_mask   = (const float*)d_in[4];
    const float* w_conv   = (const float*)d_in[5];
    float* out = (float*)d_out;

    _Float16* wpk_h = (_Float16*)d_ws;                   // 73,728 halves
    _Float16* wpk2  = wpk_h + 73728;                     // 18,432 halves
    _Float16* xtb   = wpk2 + 18432;                      // 8,388,608 halves (16.8 MB)

    transpose_x<<<1024, 256, 0, stream>>>(x, xtb);
    repack_w<<<288, 256, 0, stream>>>(w_conv, wpk_h);
    repack_w2<<<72, 256, 0, stream>>>(w_offset, w_mask, wpk2);
    deform_fused<<<2048, 256, 0, stream>>>(xtb, wpk_h, wpk2, b_offset, b_mask, out);
}